// Round 1
// baseline (194.789 us; speedup 1.0000x reference)
//
#include <hip/hip_runtime.h>
#include <math.h>

// CrossGeometricStructureEmbedding — fused geometry + sinusoidal embedding +
// 2x (E @ W^T) GEMM (bf16 MFMA) + max-over-anchors + bias.
// B=1, N=4096, K=64, H=O=256.
//
// One block per point n. LDS holds the 64x256 bf16 embedding tile (padded
// stride 264 shorts -> 2-way LDS bank aliasing only, free on gfx950).
// 4 waves each own a 64-channel output strip; 16x16x32 bf16 MFMA, 4x4 tiles.
// W is pre-converted fp32->bf16 into d_ws by a prep kernel; row-major W rows
// are exactly the B-fragment order (lane reads 8 contiguous h of row o).

typedef __attribute__((ext_vector_type(8))) short short8;
typedef __attribute__((ext_vector_type(4))) float f32x4;

#define HH 256
#define KK 64

__device__ __forceinline__ unsigned short f2bf(float f) {
    union { float f; unsigned int u; } v; v.f = f;
    unsigned int r = v.u + 0x7fffu + ((v.u >> 16) & 1u);  // RNE
    return (unsigned short)(r >> 16);
}

__global__ __launch_bounds__(256)
void prep_w_kernel(const float* __restrict__ Wa, const float* __restrict__ Wd,
                   unsigned short* __restrict__ wbf) {
    int i = blockIdx.x * 256 + threadIdx.x;
    if (i < HH * HH) {
        wbf[i] = f2bf(Wd[i]);             // [0, 65536): Wd bf16
        wbf[HH * HH + i] = f2bf(Wa[i]);   // [65536, 131072): Wa bf16
    }
}

__global__ __launch_bounds__(256)
void cgse_kernel(const float* __restrict__ points,
                 const float* __restrict__ anchors,
                 const unsigned short* __restrict__ wdbf,
                 const unsigned short* __restrict__ wabf,
                 const float* __restrict__ ba,
                 const float* __restrict__ bd,
                 float* __restrict__ out) {
    __shared__ __align__(16) unsigned short E[64][264];  // 33.8 KB, pad+8 shorts
    __shared__ float xd[64], xa[64], divt[128], anch[192];

    const int tid = threadIdx.x;
    const int p = blockIdx.x;
    const int wave = tid >> 6, lane = tid & 63;
    const int quad = lane >> 4, l16 = lane & 15;

    if (tid < 192) anch[tid] = anchors[tid];
    // div_term[i] = exp(2i * -ln(10000)/256), i = 0..127
    if (tid < 128) divt[tid] = __expf((float)(2 * tid) * (-9.210340371976184f / 256.0f));
    __syncthreads();

    const float px = points[p * 3 + 0], py = points[p * 3 + 1], pz = points[p * 3 + 2];

    if (tid < 64) {
        const int k = tid, k2 = (tid + 1) & 63;  // roll(-1)
        const float r1x = px - anch[k * 3 + 0], r1y = py - anch[k * 3 + 1], r1z = pz - anch[k * 3 + 2];
        const float r2x = px - anch[k2 * 3 + 0], r2y = py - anch[k2 * 3 + 1], r2z = pz - anch[k2 * 3 + 2];
        xd[k] = sqrtf(r1x * r1x + r1y * r1y + r1z * r1z) * 5.0f;  // 1/SIGMA_D
        const float cx = r1y * r2z - r1z * r2y;
        const float cy = r1z * r2x - r1x * r2z;
        const float cz = r1x * r2y - r1y * r2x;
        const float sv = sqrtf(cx * cx + cy * cy + cz * cz);
        const float cv = r1x * r2x + r1y * r2y + r1z * r2z;
        xa[k] = atan2f(sv, cv) * 3.8197186342054885f;  // 180/(15*pi)
    }
    __syncthreads();

    // Fill E[r][2i]=sin(x_r*div_i), E[r][2i+1]=cos. Thread t: row t>>2, 32 i's.
    auto fill = [&](const float* __restrict__ xs) {
        const int r = tid >> 2;
        const int ib = (tid & 3) * 32;
        const float x = xs[r];
        unsigned int* row = (unsigned int*)&E[r][0];
        #pragma unroll 8
        for (int j = 0; j < 32; ++j) {
            const int i = ib + j;
            const float om = x * divt[i];
            float s, c;
            __sincosf(om, &s, &c);
            row[i] = (unsigned int)f2bf(s) | ((unsigned int)f2bf(c) << 16);
        }
    };

    // GEMM wave strip: D[m=0..63][n=0..63] = sum_h E[m][h] * W[nbase+n][h];
    // then column-wise max over the 64 rows. Result valid on lanes 0..15.
    auto gemm_max = [&](const unsigned short* __restrict__ Wbf, float* mx) {
        f32x4 acc[4][4];
        #pragma unroll
        for (int mt = 0; mt < 4; ++mt)
            #pragma unroll
            for (int nt = 0; nt < 4; ++nt)
                acc[mt][nt] = (f32x4){0.f, 0.f, 0.f, 0.f};
        const unsigned short* wbase = Wbf + (wave * 64 + l16) * HH + quad * 8;
        #pragma unroll
        for (int ks = 0; ks < 8; ++ks) {
            const int k0 = ks * 32 + quad * 8;
            short8 afr[4], bfr[4];
            #pragma unroll
            for (int mt = 0; mt < 4; ++mt)
                afr[mt] = *(const short8*)&E[mt * 16 + l16][k0];
            #pragma unroll
            for (int nt = 0; nt < 4; ++nt)
                bfr[nt] = *(const short8*)(wbase + nt * 16 * HH + ks * 32);
            #pragma unroll
            for (int nt = 0; nt < 4; ++nt)
                #pragma unroll
                for (int mt = 0; mt < 4; ++mt)
                    acc[mt][nt] = __builtin_amdgcn_mfma_f32_16x16x32_bf16(
                        afr[mt], bfr[nt], acc[mt][nt], 0, 0, 0);
        }
        #pragma unroll
        for (int nt = 0; nt < 4; ++nt) {
            float m = fmaxf(fmaxf(acc[0][nt][0], acc[0][nt][1]),
                            fmaxf(acc[0][nt][2], acc[0][nt][3]));
            #pragma unroll
            for (int mt = 1; mt < 4; ++mt)
                m = fmaxf(m, fmaxf(fmaxf(acc[mt][nt][0], acc[mt][nt][1]),
                                   fmaxf(acc[mt][nt][2], acc[mt][nt][3])));
            m = fmaxf(m, __shfl_down(m, 32));
            m = fmaxf(m, __shfl_down(m, 16));  // lanes 0..15: max over all 64 rows
            mx[nt] = m;
        }
    };

    float dmx[4], amx[4];
    fill(xd);
    __syncthreads();
    gemm_max(wdbf, dmx);
    __syncthreads();
    fill(xa);
    __syncthreads();
    gemm_max(wabf, amx);

    if (lane < 16) {
        #pragma unroll
        for (int nt = 0; nt < 4; ++nt) {
            const int col = wave * 64 + nt * 16 + l16;
            out[p * HH + col] = dmx[nt] + amx[nt] + bd[col] + ba[col];
        }
    }
}

extern "C" void kernel_launch(void* const* d_in, const int* in_sizes, int n_in,
                              void* d_out, int out_size, void* d_ws, size_t ws_size,
                              hipStream_t stream) {
    const float* points  = (const float*)d_in[0];
    const float* anchors = (const float*)d_in[1];
    // d_in[2] = cor_score: unused by the reference
    const float* Wa = (const float*)d_in[3];
    const float* ba = (const float*)d_in[4];
    const float* Wd = (const float*)d_in[5];
    const float* bd = (const float*)d_in[6];

    unsigned short* wbf = (unsigned short*)d_ws;  // 256 KB scratch: Wd|Wa in bf16

    hipLaunchKernelGGL(prep_w_kernel, dim3(256), dim3(256), 0, stream, Wa, Wd, wbf);
    hipLaunchKernelGGL(cgse_kernel, dim3(4096), dim3(256), 0, stream,
                       points, anchors, wbf, wbf + HH * HH, ba, bd, (float*)d_out);
}

// Round 2
// 135.987 us; speedup vs baseline: 1.4324x; 1.4324x over previous
//
#include <hip/hip_runtime.h>
#include <hip/hip_bf16.h>
#include <math.h>

// CrossGeometricStructureEmbedding, round 2: pipelined fused design.
// Grid = 2 x 256 blocks (even blockIdx = d-embedding, odd = a-embedding).
// Each block: 16 points, one W matrix. Per wave: 64 output cols, whole W-strip
// (64 cols x 256 k, bf16) register-resident (128 VGPRs). E tile (64x256 bf16)
// double-buffered in LDS; the ks-loop fuses "fill chunk for point p+1" with
// "16 MFMAs for point p" so sincos-VALU, LDS and MFMA pipes overlap.
// One __syncthreads per point. Fill writes use the exact b128 chunks the
// A-fragments read -> even 8-per-bank LDS access (structural minimum).
// d-blocks add (ba+bd); both types unsafeAtomicAdd into zeroed d_out.

typedef __attribute__((ext_vector_type(8))) short short8;
typedef __attribute__((ext_vector_type(4))) float f32x4;
typedef __attribute__((ext_vector_type(4))) unsigned int uint4v;

#define HH 256
#define P_PTS 16
#define NPTS 4096

__device__ __forceinline__ unsigned short f2bf(float f) {
    union { float f; unsigned int u; } v; v.f = f;
    unsigned int r = v.u + 0x7fffu + ((v.u >> 16) & 1u);  // RNE
    return (unsigned short)(r >> 16);
}

__device__ __forceinline__ unsigned int pack_sc(float s, float c) {
    union { __hip_bfloat162 h; unsigned int u; } v;
    v.h = __float22bfloat162_rn(make_float2(s, c));  // low = sin, high = cos
    return v.u;
}

__global__ __launch_bounds__(256)
void prep_w_kernel(const float* __restrict__ Wa, const float* __restrict__ Wd,
                   unsigned short* __restrict__ wbf) {
    int i = blockIdx.x * 256 + threadIdx.x;
    if (i < HH * HH) {
        wbf[i] = f2bf(Wd[i]);             // [0, 65536): Wd bf16
        wbf[HH * HH + i] = f2bf(Wa[i]);   // [65536, 131072): Wa bf16
    }
}

__global__ __launch_bounds__(256, 2)
void cgse_main(const float* __restrict__ points,
               const float* __restrict__ anchors,
               const unsigned short* __restrict__ wbf,
               const float* __restrict__ ba,
               const float* __restrict__ bd,
               float* __restrict__ out) {
    __shared__ __align__(16) unsigned short E[2][64][264];  // 67.6 KB dbuf
    __shared__ float xs[2][64];
    __shared__ float anch[192];

    const int tid = threadIdx.x;
    const int wave = tid >> 6, lane = tid & 63;
    const int quad = lane >> 4, l16 = lane & 15;
    const int type = blockIdx.x & 1;            // 0 = d (Wd), 1 = a (Wa)
    const int base = (blockIdx.x >> 1) * P_PTS;

    // ---- W strip into registers: 4 nt-tiles x 8 ks-chunks x short8 = 128 VGPRs
    const unsigned short* W = wbf + type * (HH * HH);
    short8 bw[4][8];
    {
        const unsigned short* wb = W + (wave * 64 + l16) * HH + quad * 8;
        #pragma unroll
        for (int nt = 0; nt < 4; ++nt)
            #pragma unroll
            for (int ks = 0; ks < 8; ++ks)
                bw[nt][ks] = *(const short8*)(wb + nt * 16 * HH + ks * 32);
    }

    // biases: only the d-type blocks add (ba + bd); a-type adds raw max
    float bias[4];
    #pragma unroll
    for (int nt = 0; nt < 4; ++nt) {
        const int c = wave * 64 + nt * 16 + l16;
        bias[nt] = (type == 0) ? (ba[c] + bd[c]) : 0.0f;
    }

    // per-lane div_term bases: pair index i = ks*16 + quad*4 + j
    // dt0[j] = 10000^(-(quad*4+j)/128); rk[ks] = 10000^(-ks/8)
    float dt0[4];
    #pragma unroll
    for (int j = 0; j < 4; ++j)
        dt0[j] = __expf(-(float)(quad * 4 + j) * 0.0719557841560639f);
    const float rk[8] = {1.0f, 0.31622776601683794f, 0.1f, 0.031622776601683794f,
                         0.01f, 0.0031622776601683794f, 0.001f, 0.00031622776601683794f};

    if (tid < 192) anch[tid] = anchors[tid];
    __syncthreads();

    auto geom = [&](int pn, int slot) {
        if (tid < 64) {
            const float px = points[pn * 3 + 0], py = points[pn * 3 + 1], pz = points[pn * 3 + 2];
            const int k = tid;
            const float r1x = px - anch[k * 3 + 0];
            const float r1y = py - anch[k * 3 + 1];
            const float r1z = pz - anch[k * 3 + 2];
            float v;
            if (type == 0) {
                v = sqrtf(r1x * r1x + r1y * r1y + r1z * r1z) * 5.0f;  // /SIGMA_D
            } else {
                const int k2 = (k + 1) & 63;  // roll(-1)
                const float r2x = px - anch[k2 * 3 + 0];
                const float r2y = py - anch[k2 * 3 + 1];
                const float r2z = pz - anch[k2 * 3 + 2];
                const float cx = r1y * r2z - r1z * r2y;
                const float cy = r1z * r2x - r1x * r2z;
                const float cz = r1x * r2y - r1y * r2x;
                const float sv = sqrtf(cx * cx + cy * cy + cz * cz);
                const float cv = r1x * r2x + r1y * r2y + r1z * r2z;
                v = atan2f(sv, cv) * 3.8197186342054885f;  // *180/(15*pi)
            }
            xs[slot][k] = v;
        }
    };

    const int frow = wave * 16 + l16;  // row this thread fills

    auto fill_chunk = [&](int fb, int ks, const float* xq, float rkv) {
        uint4v w;
        #pragma unroll
        for (int j = 0; j < 4; ++j) {
            float s, c;
            __sincosf(xq[j] * rkv, &s, &c);
            w[j] = pack_sc(s, c);
        }
        *(uint4v*)&E[fb][frow][ks * 32 + quad * 8] = w;
    };

    // prologue: geometry for p0, p1; full fill of buf0 with p0
    geom(base + 0, 0);
    geom(base + 1, 1);
    __syncthreads();
    {
        const float xv = xs[0][frow];
        float xq[4];
        #pragma unroll
        for (int j = 0; j < 4; ++j) xq[j] = xv * dt0[j];
        #pragma unroll
        for (int ks = 0; ks < 8; ++ks) fill_chunk(0, ks, xq, rk[ks]);
    }

    for (int q = 0; q < P_PTS; ++q) {
        __syncthreads();  // buf(q&1) filled; buf((q+1)&1) free; xs((q+1)&1) ready
        const int b = q & 1, fb = b ^ 1;
        const bool do_fill = (q + 1) < P_PTS;

        float xq[4];
        if (do_fill) {
            const float xv = xs[(q + 1) & 1][frow];
            #pragma unroll
            for (int j = 0; j < 4; ++j) xq[j] = xv * dt0[j];
        }

        f32x4 acc[4][4];
        #pragma unroll
        for (int mt = 0; mt < 4; ++mt)
            #pragma unroll
            for (int nt = 0; nt < 4; ++nt)
                acc[mt][nt] = (f32x4){0.f, 0.f, 0.f, 0.f};

        #pragma unroll
        for (int ks = 0; ks < 8; ++ks) {
            if (do_fill) fill_chunk(fb, ks, xq, rk[ks]);  // overlaps MFMA below
            short8 afr[4];
            #pragma unroll
            for (int mt = 0; mt < 4; ++mt)
                afr[mt] = *(const short8*)&E[b][mt * 16 + l16][ks * 32 + quad * 8];
            #pragma unroll
            for (int nt = 0; nt < 4; ++nt)
                #pragma unroll
                for (int mt = 0; mt < 4; ++mt)
                    acc[mt][nt] = __builtin_amdgcn_mfma_f32_16x16x32_bf16(
                        afr[mt], bw[nt][ks], acc[mt][nt], 0, 0, 0);
        }

        if (q + 2 < P_PTS) geom(base + q + 2, q & 1);  // for fill 2 phases ahead

        #pragma unroll
        for (int nt = 0; nt < 4; ++nt) {
            float m = fmaxf(fmaxf(acc[0][nt][0], acc[0][nt][1]),
                            fmaxf(acc[0][nt][2], acc[0][nt][3]));
            #pragma unroll
            for (int mt = 1; mt < 4; ++mt)
                m = fmaxf(m, fmaxf(fmaxf(acc[mt][nt][0], acc[mt][nt][1]),
                                   fmaxf(acc[mt][nt][2], acc[mt][nt][3])));
            m = fmaxf(m, __shfl_down(m, 32));
            m = fmaxf(m, __shfl_down(m, 16));  // lanes 0..15: max over 64 anchors
            if (lane < 16)
                unsafeAtomicAdd(&out[(base + q) * HH + wave * 64 + nt * 16 + l16],
                                m + bias[nt]);
        }
    }
}

extern "C" void kernel_launch(void* const* d_in, const int* in_sizes, int n_in,
                              void* d_out, int out_size, void* d_ws, size_t ws_size,
                              hipStream_t stream) {
    const float* points  = (const float*)d_in[0];
    const float* anchors = (const float*)d_in[1];
    // d_in[2] = cor_score: unused by the reference
    const float* Wa = (const float*)d_in[3];
    const float* ba = (const float*)d_in[4];
    const float* Wd = (const float*)d_in[5];
    const float* bd = (const float*)d_in[6];

    unsigned short* wbf = (unsigned short*)d_ws;  // 256 KB: Wd|Wa bf16

    hipMemsetAsync(d_out, 0, (size_t)NPTS * HH * sizeof(float), stream);
    hipLaunchKernelGGL(prep_w_kernel, dim3(256), dim3(256), 0, stream, Wa, Wd, wbf);
    hipLaunchKernelGGL(cgse_main, dim3(2 * (NPTS / P_PTS)), dim3(256), 0, stream,
                       points, anchors, wbf, ba, bd, (float*)d_out);
}